// Round 8
// baseline (2271.082 us; speedup 1.0000x reference)
//
#include <hip/hip_runtime.h>

typedef unsigned short u16;
typedef __attribute__((ext_vector_type(8))) short short8;
typedef __attribute__((ext_vector_type(4))) float f32x4;

#define NN 128000
#define EE 512000
#define GB 128

#define GLDS16(g, l)                                                     \
  __builtin_amdgcn_global_load_lds(                                      \
      (const __attribute__((address_space(1))) unsigned int*)(g),        \
      (__attribute__((address_space(3))) unsigned int*)(l), 16, 0, 0)

__device__ __forceinline__ float u2f(u16 u) {
  union { unsigned u32; float f; } v; v.u32 = ((unsigned)u) << 16; return v.f;
}
__device__ __forceinline__ u16 f2bf(float x) {
  union { float f; unsigned u; } v; v.f = x;
  unsigned r = v.u + 0x7FFF + ((v.u >> 16) & 1);
  return (u16)(r >> 16);
}

// ---- weight prep: lin_wT[33][256] f32, w1T[78][64] f32,
// ---- w2t[k][o][c] bf16 (3x256x64),
// ---- w3r: wave-coalesced B fragments [k][ot4][wn4][j4][cb8][quad4][l16_16][i8] bf16
// ----      (k stride 262144 u16, ot stride 65536, wn stride 16384, j stride 4096, cb 512)
__global__ void k_transpose(const float* lin_w, const float* w1, const float* w2, const float* w3,
                            float* lin_wT, float* w1T, u16* w2t, u16* w3r) {
  int idx = blockIdx.x * 256 + threadIdx.x;
  if (idx < 8448) { int i = idx >> 8, o = idx & 255; lin_wT[idx] = lin_w[o * 33 + i]; return; }
  idx -= 8448;
  if (idx < 4992) { int o = idx & 63, ck = idx >> 6; w1T[idx] = w1[o * 78 + ck]; return; }
  idx -= 4992;
  if (idx < 49152) {
    int c = idx & 63, o = (idx >> 6) & 255, k = idx >> 14;
    w2t[idx] = f2bf(w2[o * 192 + c * 3 + k]);
    return;
  }
  idx -= 49152;
  if (idx < 1310720) {
    int k    = idx >> 18;
    int r    = idx & 262143;
    int ot   = r >> 16;
    int wn   = (r >> 14) & 3;
    int j    = (r >> 12) & 3;
    int cb   = (r >> 9) & 7;
    int quad = (r >> 7) & 3;
    int l16  = (r >> 3) & 15;
    int i    = r & 7;
    int o = ot * 256 + wn * 64 + j * 16 + l16;
    int c = cb * 32 + quad * 8 + i;
    w3r[idx] = f2bf(w3[o * 1280 + c * 5 + k]);
  }
}

// ---- in-degree over col; per-graph edge histogram; graph boundaries
__global__ void k_deg_start(const int* ei, const int* batch, int* deg, int* start, int* hist) {
  __shared__ int lh[GB];
  int tid = threadIdx.x, blk = blockIdx.x;
  if (tid < GB) lh[tid] = 0;
  __syncthreads();
  int e0 = blk * 1024;
#pragma unroll
  for (int t = 0; t < 4; t++) {
    int e = e0 + t * 256 + tid;
    int col = ei[EE + e];
    atomicAdd(&deg[col], 1);
    atomicAdd(&lh[batch[col]], 1);
  }
  int i = blk * 256 + tid;
  int b = batch[i];
  if (i == 0) start[0] = 0;
  else if (b != batch[i - 1]) start[b] = i;
  if (i == NN - 1) start[GB] = NN;
  __syncthreads();
  if (tid < GB && lh[tid]) atomicAdd(&hist[tid * 16], lh[tid]);
}

// ---- exclusive prefix over 128 bins; init padded cursors
__global__ void k_prefix(const int* hist, int* off, int* cursor) {
  __shared__ int h[GB];
  int tid = threadIdx.x;
  h[tid] = hist[tid * 16];
  __syncthreads();
  int s = 0;
  for (int j = 0; j < tid; j++) s += h[j];
  off[tid] = s;
  cursor[tid * 16] = s;
  if (tid == GB - 1) off[GB] = s + h[GB - 1];
}

// ---- xw[n][c] = x[n] . lin_w[c] (bf16);  dis[n]
__global__ void k_xw(const float* x, const float* lin_wT, const int* deg, u16* xw, float* dis) {
  __shared__ float xs[32][34];
  int tid = threadIdx.x, n0 = blockIdx.x * 32;
  int q = tid >> 6, lane = tid & 63;
  for (int n = q; n < 32; n += 4)
    if (lane < 33) xs[n][lane] = x[(n0 + n) * 33 + lane];
  float w[33];
#pragma unroll
  for (int i = 0; i < 33; i++) w[i] = lin_wT[i * 256 + tid];
  __syncthreads();
  for (int n = 0; n < 32; n++) {
    float acc = 0.f;
#pragma unroll
    for (int i = 0; i < 33; i++) acc += w[i] * xs[n][i];
    xw[(size_t)(n0 + n) * 256 + tid] = f2bf(acc);
  }
  if (tid < 32) { int d = deg[n0 + tid]; dis[n0 + tid] = d > 0 ? rsqrtf((float)d) : 0.f; }
}

// ---- bucket edges by graph of col
__global__ void k_scatter(const int* ei, const int* batch, const float* dis,
                          int* cursor, uint2* bucket) {
  __shared__ int lh[GB];
  __shared__ int lbase[GB];
  int tid = threadIdx.x, blk = blockIdx.x;
  if (tid < GB) lh[tid] = 0;
  __syncthreads();
  int e0 = blk * 1024;
  int row[4], g[4], rk[4]; float nrm[4];
#pragma unroll
  for (int t = 0; t < 4; t++) {
    int e = e0 + t * 256 + tid;
    int r = ei[e], c = ei[EE + e];
    row[t] = r;
    g[t] = batch[c];
    nrm[t] = dis[r] * dis[c];
    rk[t] = atomicAdd(&lh[g[t]], 1);
  }
  __syncthreads();
  if (tid < GB && lh[tid]) lbase[tid] = atomicAdd(&cursor[tid * 16], lh[tid]);
  __syncthreads();
#pragma unroll
  for (int t = 0; t < 4; t++) {
    uint2 v; v.x = (unsigned)row[t]; v.y = __float_as_uint(nrm[t]);
    bucket[lbase[g[t]] + rk[t]] = v;
  }
}

// ---- per-graph gather-accumulate
__global__ void k_gather(const uint2* bucket, const int* off, const u16* xw, float* gsum) {
  __shared__ float red[4][256];
  int tid = threadIdx.x;
  int s = blockIdx.x, g = blockIdx.y;
  int lo = off[g], hi = off[g + 1];
  int cnt = hi - lo;
  int per = (cnt + 7) >> 3;
  int b0 = lo + s * per, b1 = min(b0 + per, hi);
  int lane = tid & 63, wid = tid >> 6;
  f32x4 acc = {0.f, 0.f, 0.f, 0.f};
  const u16* xbase = xw + lane * 4;
#pragma unroll 4
  for (int e = b0 + wid; e < b1; e += 4) {
    uint2 be = bucket[e];
    float nrm = __uint_as_float(be.y);
    ushort4 v = *(const ushort4*)(xbase + (size_t)be.x * 256);
    acc.x = fmaf(nrm, u2f(v.x), acc.x);
    acc.y = fmaf(nrm, u2f(v.y), acc.y);
    acc.z = fmaf(nrm, u2f(v.z), acc.z);
    acc.w = fmaf(nrm, u2f(v.w), acc.w);
  }
  *(f32x4*)&red[wid][lane * 4] = acc;
  __syncthreads();
  float v = red[0][tid] + red[1][tid] + red[2][tid] + red[3][tid];
  if (v != 0.f) atomicAdd(&gsum[tid * 128 + g], v);
}

// ---- conv1: target[bl][26][1000] -> h1T[bl][l<998][64] bf16 channel-last (relu)
__global__ void k_conv1(const float* target, const float* w1T, const float* b1, u16* h1T) {
  __shared__ float ts[26][132];
  __shared__ float wls[78 * 64];
  int tid = threadIdx.x, lt = blockIdx.x, bl = blockIdx.y;
  int l0 = lt * 128;
  int q = tid >> 6, lane = tid & 63;
  for (int c = q; c < 26; c += 4)
    for (int i = lane; i < 130; i += 64)
      ts[c][i] = target[(bl * 26 + c) * 1000 + min(l0 + i, 999)];
  for (int i = tid; i < 4992; i += 256) wls[i] = w1T[i];
  __syncthreads();
  int o = tid & 63, wid = tid >> 6;
  float w[78];
#pragma unroll
  for (int i = 0; i < 78; i++) w[i] = wls[i * 64 + o];
  float bias = b1[o];
  for (int t = 0; t < 32; t++) {
    int li = wid * 32 + t;
    float acc = bias;
#pragma unroll
    for (int c = 0; c < 26; c++)
#pragma unroll
      for (int k = 0; k < 3; k++) acc += ts[c][li + k] * w[c * 3 + k];
    int lg = l0 + li;
    if (lg < 998) h1T[((size_t)bl * 1000 + lg) * 64 + o] = f2bf(fmaxf(acc, 0.f));
  }
}

// ---- conv2 as 3 shifted GEMMs via MFMA: h1T[bl][1000][64] x w2t -> h2T[bl][996][256] bf16
__global__ void k_conv2(const u16* h1T, const u16* w2t, const float* b2, u16* h2T) {
  __shared__ __align__(16) u16 als[132 * 32];
  __shared__ __align__(16) u16 bls[3 * 128 * 32];
  int tid = threadIdx.x;
  int lt = blockIdx.x, ot = blockIdx.y, bl = blockIdx.z;
  int l0 = lt * 128, o0 = ot * 128;
  int lane = tid & 63, wid = tid >> 6;
  int wm = wid >> 1, wn = wid & 1;
  int quad = lane >> 4, l16 = lane & 15;
  const f32x4 zero = {0.f, 0.f, 0.f, 0.f};
  f32x4 acc[4][4];
#pragma unroll
  for (int i = 0; i < 4; i++)
#pragma unroll
    for (int j = 0; j < 4; j++) acc[i][j] = zero;
  for (int cb = 0; cb < 2; cb++) {
    int c0 = cb * 32;
#pragma unroll
    for (int rr = 0; rr < 2; rr++) {
      int cid = rr * 256 + wid * 64 + lane;
      int row = cid >> 2, ch = (cid & 3) ^ (row & 3);
      GLDS16(h1T + ((size_t)bl * 1000 + min(l0 + row, 997)) * 64 + c0 + ch * 8,
             als + (rr * 256 + wid * 64) * 8);
    }
    if (wid == 0 && lane < 8) {
      int cid = 512 + lane;
      int row = cid >> 2, ch = (cid & 3) ^ (row & 3);
      GLDS16(h1T + ((size_t)bl * 1000 + min(l0 + row, 997)) * 64 + c0 + ch * 8, als + 512 * 8);
    }
#pragma unroll
    for (int rr = 0; rr < 6; rr++) {
      int cid = rr * 256 + wid * 64 + lane;
      int rko = cid >> 2, k = rko >> 7, o = rko & 127;
      int ch = (cid & 3) ^ (rko & 3);
      GLDS16(w2t + ((size_t)(k * 256 + o0 + o)) * 64 + c0 + ch * 8,
             bls + (rr * 256 + wid * 64) * 8);
    }
    __syncthreads();
#pragma unroll
    for (int k = 0; k < 3; k++) {
      short8 af[4], bfr[4];
#pragma unroll
      for (int i = 0; i < 4; i++) {
        int row = k + wm * 64 + i * 16 + l16;
        af[i] = *(const short8*)(als + row * 32 + ((quad ^ (row & 3)) * 8));
      }
#pragma unroll
      for (int j = 0; j < 4; j++) {
        int rowB = wn * 64 + j * 16 + l16;
        bfr[j] = *(const short8*)(bls + (k * 128 + rowB) * 32 + ((quad ^ (rowB & 3)) * 8));
      }
#pragma unroll
      for (int i = 0; i < 4; i++)
#pragma unroll
        for (int j = 0; j < 4; j++)
          acc[i][j] = __builtin_amdgcn_mfma_f32_16x16x32_bf16(af[i], bfr[j], acc[i][j], 0, 0, 0);
    }
    __syncthreads();
  }
#pragma unroll
  for (int j = 0; j < 4; j++) {
    int col = o0 + wn * 64 + j * 16 + l16;
    float bias = b2[col];
#pragma unroll
    for (int i = 0; i < 4; i++)
#pragma unroll
      for (int r = 0; r < 4; r++) {
        int lg = l0 + wm * 64 + i * 16 + quad * 4 + r;
        if (lg < 996)
          h2T[((size_t)bl * 996 + lg) * 256 + col] = f2bf(fmaxf(acc[i][j][r] + bias, 0.f));
      }
  }
}

// ---- conv3: wave tile 128l x 64o (i=8, j=4; waves = 4 disjoint wn). A staged once per lt
// ---- as full 136x256 window (69.6 KB, 32-slot swizzle, 2-way-free reads); B global->VGPR
// ---- pipelined (halved traffic vs wm-split). 5 shifted GEMMs, fused max-pool+bias+relu.
__global__ void __launch_bounds__(256, 2)
k_conv3(const u16* h2T, const u16* w3r, const float* b3, float* pooledT) {
  __shared__ __align__(16) u16 als[136 * 256];   // 69632 B
  __shared__ float mbuf[256];
  int bid = blockIdx.x;
  int xc = bid & 7, rr0 = bid >> 3;            // 64 blocks per XCD: 16 bl x 4 ot
  int ot = rr0 & 3, bl = xc * 16 + (rr0 >> 2);
  int o0 = ot * 256;
  int tid = threadIdx.x;
  int lane = tid & 63, wn = tid >> 6;
  int quad = lane >> 4, l16 = lane & 15;
  float omax[4];
#pragma unroll
  for (int j = 0; j < 4; j++) omax[j] = -3.0e38f;
  const f32x4 zero = {0.f, 0.f, 0.f, 0.f};
  // per-wave B base: [k][ot][wn][j][cb][lane*8]
  const u16* wbase = w3r + ((size_t)(ot * 4 + wn)) * 16384 + lane * 8;
  for (int lt = 0; lt < 8; lt++) {
    int l0 = lt * 128;
    f32x4 acc[8][4];
#pragma unroll
    for (int i = 0; i < 8; i++)
#pragma unroll
      for (int j = 0; j < 4; j++) acc[i][j] = zero;
    // stage A window: 136 rows x 32 chunks = 4352 chunks = 17 rounds; slot=(cc+row)&31
#pragma unroll
    for (int rr = 0; rr < 17; rr++) {
      int cid = rr * 256 + wn * 64 + lane;
      int row = cid >> 5, pp = cid & 31;
      int cc = (pp - row) & 31;
      GLDS16(h2T + ((size_t)bl * 996 + min(l0 + row, 995)) * 256 + cc * 8,
             als + (rr * 256 + wn * 64) * 8);
    }
    // prefetch B (cb=0, k=0)
    short8 breg[4];
#pragma unroll
    for (int j = 0; j < 4; j++)
      breg[j] = *(const short8*)(wbase + (size_t)j * 4096);
    __syncthreads();
#pragma unroll
    for (int cb = 0; cb < 8; cb++) {
#pragma unroll
      for (int k = 0; k < 5; k++) {
        short8 bcur[4];
#pragma unroll
        for (int j = 0; j < 4; j++) bcur[j] = breg[j];
        int nk = (k == 4) ? 0 : k + 1;
        int ncb = (k == 4) ? cb + 1 : cb;
        if (ncb == 8) { ncb = 7; nk = 4; }   // clamp: redundant reload on final iter
#pragma unroll
        for (int j = 0; j < 4; j++)
          breg[j] = *(const short8*)(wbase + (size_t)nk * 262144 + (size_t)j * 4096 +
                                     (size_t)ncb * 512);
#pragma unroll
        for (int i = 0; i < 8; i++) {
          int row = k + i * 16 + l16;
          int slot = (cb * 4 + quad + row) & 31;
          short8 af = *(const short8*)(als + row * 256 + slot * 8);
#pragma unroll
          for (int j = 0; j < 4; j++)
            acc[i][j] = __builtin_amdgcn_mfma_f32_16x16x32_bf16(af, bcur[j], acc[i][j], 0, 0, 0);
        }
      }
    }
    __syncthreads();
    // fold l-tile into running per-o max (mask rows >= 992)
#pragma unroll
    for (int i = 0; i < 8; i++) {
#pragma unroll
      for (int r = 0; r < 4; r++) {
        int lg = l0 + i * 16 + quad * 4 + r;
        if (lg < 992) {
#pragma unroll
          for (int j = 0; j < 4; j++) omax[j] = fmaxf(omax[j], acc[i][j][r]);
        }
      }
    }
  }
#pragma unroll
  for (int j = 0; j < 4; j++) {
    omax[j] = fmaxf(omax[j], __shfl_xor(omax[j], 16, 64));
    omax[j] = fmaxf(omax[j], __shfl_xor(omax[j], 32, 64));
  }
  if (quad == 0) {
#pragma unroll
    for (int j = 0; j < 4; j++) mbuf[wn * 64 + j * 16 + l16] = omax[j];
  }
  __syncthreads();
  {
    float v = mbuf[tid] + b3[o0 + tid];
    pooledT[(size_t)(o0 + tid) * 128 + bl] = fmaxf(v, 0.f);
  }
}

// ---- z0T[r][b]
__global__ void k_z0(const float* gsum, const int* start, const float* lin_b, const float* tgtT,
                     float* z0T) {
  int idx = blockIdx.x * 256 + threadIdx.x;
  int r = idx >> 7, bb = idx & 127;
  float v;
  if (r < 256) {
    float c = (float)(start[bb + 1] - start[bb]);
    v = gsum[idx] / c + lin_b[r];
  } else {
    v = tgtT[(r - 256) * 128 + bb];
  }
  z0T[idx] = v;
}

// ---- fc layer on transposed activations
__global__ void k_fc(const float* zT, const float* W, const float* bias, float* outT,
                     int K, int O, int relu, float* final_out) {
  __shared__ float wls[2][1024];
  int tid = threadIdx.x;
  int o0 = blockIdx.x * 2;
  for (int idx = tid; idx < 2 * K; idx += 256) {
    int oo = idx >= K ? 1 : 0;
    int i = idx - oo * K;
    if (o0 + oo < O) wls[oo][i] = W[(size_t)(o0 + oo) * K + i];
  }
  __syncthreads();
  int osub = tid >> 7, bb = tid & 127;
  int o = o0 + osub;
  if (o >= O) return;
  float acc = 0.f;
#pragma unroll 8
  for (int i = 0; i < K; i++) acc += wls[osub][i] * zT[i * 128 + bb];
  acc += bias[o];
  if (relu) acc = fmaxf(acc, 0.f);
  if (final_out) {
    if (o == 0) final_out[bb] = acc;
  } else {
    outT[(size_t)o * 128 + bb] = acc;
  }
}

extern "C" void kernel_launch(void* const* d_in, const int* in_sizes, int n_in,
                              void* d_out, int out_size, void* d_ws, size_t ws_size,
                              hipStream_t stream) {
  const float* x      = (const float*)d_in[0];
  const int*   ei     = (const int*)d_in[1];
  const int*   batch  = (const int*)d_in[2];
  const float* target = (const float*)d_in[3];
  const float* lin_w  = (const float*)d_in[4];
  const float* lin_b  = (const float*)d_in[5];
  const float* w1     = (const float*)d_in[6];
  const float* b1     = (const float*)d_in[7];
  const float* w2     = (const float*)d_in[8];
  const float* b2     = (const float*)d_in[9];
  const float* w3     = (const float*)d_in[10];
  const float* b3     = (const float*)d_in[11];
  const float* fcw    = (const float*)d_in[12];
  const float* fcb    = (const float*)d_in[13];
  const float* m1w = (const float*)d_in[14]; const float* m1b = (const float*)d_in[15];
  const float* m2w = (const float*)d_in[16]; const float* m2b = (const float*)d_in[17];
  const float* m3w = (const float*)d_in[18]; const float* m3b = (const float*)d_in[19];
  const float* m4w = (const float*)d_in[20]; const float* m4b = (const float*)d_in[21];

  char* ws = (char*)d_ws;
  size_t ofs = 0;
  auto alloc = [&](size_t bytes) -> void* {
    void* p = ws + ofs;
    ofs = (ofs + bytes + 255) & ~(size_t)255;
    return p;
  };
  // ---- persistent region ----
  int*   deg    = (int*)alloc((size_t)NN * 4);
  float* dis    = (float*)alloc((size_t)NN * 4);
  int*   start  = (int*)alloc((size_t)(GB + 1) * 4);
  int*   hist   = (int*)alloc((size_t)GB * 16 * 4);
  int*   off    = (int*)alloc((size_t)(GB + 1) * 4);
  int*   cursor = (int*)alloc((size_t)GB * 16 * 4);
  uint2* bucket = (uint2*)alloc((size_t)EE * 8);
  float* gsum   = (float*)alloc((size_t)256 * 128 * 4);
  float* lin_wT = (float*)alloc((size_t)33 * 256 * 4);
  float* w1T    = (float*)alloc((size_t)78 * 64 * 4);
  u16*   w2t    = (u16*)alloc((size_t)3 * 256 * 64 * 2);
  u16*   w3r    = (u16*)alloc((size_t)5 * 1024 * 256 * 2);
  float* pooledT= (float*)alloc((size_t)1024 * 128 * 4);
  float* tgtT   = (float*)alloc((size_t)768 * 128 * 4);
  float* z0T    = (float*)alloc((size_t)1024 * 128 * 4);
  float* z1T    = (float*)alloc((size_t)1024 * 128 * 4);
  float* z2T    = (float*)alloc((size_t)1024 * 128 * 4);
  float* z3T    = (float*)alloc((size_t)512 * 128 * 4);
  size_t F_end = ofs;

  // ---- dynamic region: xw (GNN) aliased by h1T+h2T (CNN) ----
  u16* xw  = (u16*)(ws + F_end);
  u16* h1T = (u16*)(ws + F_end);
  u16* h2T = (u16*)(ws + F_end + (size_t)128 * 1000 * 64 * 2);

  hipMemsetAsync(deg, 0, (size_t)NN * 4, stream);
  hipMemsetAsync(hist, 0, (size_t)GB * 16 * 4, stream);
  hipMemsetAsync(gsum, 0, (size_t)256 * 128 * 4, stream);

  // ---- GNN phase ----
  k_transpose<<<5365, 256, 0, stream>>>(lin_w, w1, w2, w3, lin_wT, w1T, w2t, w3r);
  k_deg_start<<<500, 256, 0, stream>>>(ei, batch, deg, start, hist);
  k_prefix<<<1, 128, 0, stream>>>(hist, off, cursor);
  k_xw<<<4000, 256, 0, stream>>>(x, lin_wT, deg, xw, dis);
  k_scatter<<<500, 256, 0, stream>>>(ei, batch, dis, cursor, bucket);
  k_gather<<<dim3(8, GB), 256, 0, stream>>>(bucket, off, xw, gsum);

  // ---- CNN phase ----
  k_conv1<<<dim3(8, 128), 256, 0, stream>>>(target, w1T, b1, h1T);
  k_conv2<<<dim3(8, 2, 128), 256, 0, stream>>>(h1T, w2t, b2, h2T);
  k_conv3<<<512, 256, 0, stream>>>(h2T, w3r, b3, pooledT);

  // ---- head ----
  k_fc<<<384, 256, 0, stream>>>(pooledT, fcw, fcb, tgtT, 1024, 768, 1, nullptr);
  k_z0<<<512, 256, 0, stream>>>(gsum, start, lin_b, tgtT, z0T);
  k_fc<<<512, 256, 0, stream>>>(z0T, m1w, m1b, z1T, 1024, 1024, 1, nullptr);
  k_fc<<<512, 256, 0, stream>>>(z1T, m2w, m2b, z2T, 1024, 1024, 1, nullptr);
  k_fc<<<256, 256, 0, stream>>>(z2T, m3w, m3b, z3T, 1024, 512, 1, nullptr);
  k_fc<<<1, 256, 0, stream>>>(z3T, m4w, m4b, nullptr, 512, 1, 0, (float*)d_out);
}

// Round 9
// 980.432 us; speedup vs baseline: 2.3164x; 2.3164x over previous
//
#include <hip/hip_runtime.h>

typedef unsigned short u16;
typedef __attribute__((ext_vector_type(8))) short short8;
typedef __attribute__((ext_vector_type(4))) float f32x4;

#define NN 128000
#define EE 512000
#define GB 128

#define GLDS16(g, l)                                                     \
  __builtin_amdgcn_global_load_lds(                                      \
      (const __attribute__((address_space(1))) unsigned int*)(g),        \
      (__attribute__((address_space(3))) unsigned int*)(l), 16, 0, 0)

__device__ __forceinline__ float u2f(u16 u) {
  union { unsigned u32; float f; } v; v.u32 = ((unsigned)u) << 16; return v.f;
}
__device__ __forceinline__ u16 f2bf(float x) {
  union { float f; unsigned u; } v; v.f = x;
  unsigned r = v.u + 0x7FFF + ((v.u >> 16) & 1);
  return (u16)(r >> 16);
}

// ---- weight prep: lin_wT[33][256] f32, w1T[78][64] f32,
// ---- w2t[k][o][c] bf16 (3x256x64),
// ---- w3r: wave-coalesced B slabs [k][ot4][wn2][j8][cbg8][quad4][l16_16][i8] bf16
// ----      (k stride = 64*4096 = 262144 u16)  -- MATCHES round-7 k_conv3
__global__ void k_transpose(const float* lin_w, const float* w1, const float* w2, const float* w3,
                            float* lin_wT, float* w1T, u16* w2t, u16* w3r) {
  int idx = blockIdx.x * 256 + threadIdx.x;
  if (idx < 8448) { int i = idx >> 8, o = idx & 255; lin_wT[idx] = lin_w[o * 33 + i]; return; }
  idx -= 8448;
  if (idx < 4992) { int o = idx & 63, ck = idx >> 6; w1T[idx] = w1[o * 78 + ck]; return; }
  idx -= 4992;
  if (idx < 49152) {
    int c = idx & 63, o = (idx >> 6) & 255, k = idx >> 14;
    w2t[idx] = f2bf(w2[o * 192 + c * 3 + k]);
    return;
  }
  idx -= 49152;
  if (idx < 1310720) {
    int k    = idx >> 18;
    int r    = idx & 262143;
    int ot   = r >> 16;
    int wn   = (r >> 15) & 1;
    int j    = (r >> 12) & 7;
    int cbg  = (r >> 9) & 7;
    int quad = (r >> 7) & 3;
    int l16  = (r >> 3) & 15;
    int i    = r & 7;
    int o = ot * 256 + wn * 128 + j * 16 + l16;
    int c = cbg * 32 + quad * 8 + i;
    w3r[idx] = f2bf(w3[o * 1280 + c * 5 + k]);
  }
}

// ---- in-degree over col; per-graph edge histogram; graph boundaries
__global__ void k_deg_start(const int* ei, const int* batch, int* deg, int* start, int* hist) {
  __shared__ int lh[GB];
  int tid = threadIdx.x, blk = blockIdx.x;
  if (tid < GB) lh[tid] = 0;
  __syncthreads();
  int e0 = blk * 1024;
#pragma unroll
  for (int t = 0; t < 4; t++) {
    int e = e0 + t * 256 + tid;
    int col = ei[EE + e];
    atomicAdd(&deg[col], 1);
    atomicAdd(&lh[batch[col]], 1);
  }
  int i = blk * 256 + tid;
  int b = batch[i];
  if (i == 0) start[0] = 0;
  else if (b != batch[i - 1]) start[b] = i;
  if (i == NN - 1) start[GB] = NN;
  __syncthreads();
  if (tid < GB && lh[tid]) atomicAdd(&hist[tid * 16], lh[tid]);
}

// ---- exclusive prefix over 128 bins; init padded cursors
__global__ void k_prefix(const int* hist, int* off, int* cursor) {
  __shared__ int h[GB];
  int tid = threadIdx.x;
  h[tid] = hist[tid * 16];
  __syncthreads();
  int s = 0;
  for (int j = 0; j < tid; j++) s += h[j];
  off[tid] = s;
  cursor[tid * 16] = s;
  if (tid == GB - 1) off[GB] = s + h[GB - 1];
}

// ---- xw[n][c] = x[n] . lin_w[c] (bf16);  dis[n]
__global__ void k_xw(const float* x, const float* lin_wT, const int* deg, u16* xw, float* dis) {
  __shared__ float xs[32][34];
  int tid = threadIdx.x, n0 = blockIdx.x * 32;
  int q = tid >> 6, lane = tid & 63;
  for (int n = q; n < 32; n += 4)
    if (lane < 33) xs[n][lane] = x[(n0 + n) * 33 + lane];
  float w[33];
#pragma unroll
  for (int i = 0; i < 33; i++) w[i] = lin_wT[i * 256 + tid];
  __syncthreads();
  for (int n = 0; n < 32; n++) {
    float acc = 0.f;
#pragma unroll
    for (int i = 0; i < 33; i++) acc += w[i] * xs[n][i];
    xw[(size_t)(n0 + n) * 256 + tid] = f2bf(acc);
  }
  if (tid < 32) { int d = deg[n0 + tid]; dis[n0 + tid] = d > 0 ? rsqrtf((float)d) : 0.f; }
}

// ---- bucket edges by graph of col
__global__ void k_scatter(const int* ei, const int* batch, const float* dis,
                          int* cursor, uint2* bucket) {
  __shared__ int lh[GB];
  __shared__ int lbase[GB];
  int tid = threadIdx.x, blk = blockIdx.x;
  if (tid < GB) lh[tid] = 0;
  __syncthreads();
  int e0 = blk * 1024;
  int row[4], g[4], rk[4]; float nrm[4];
#pragma unroll
  for (int t = 0; t < 4; t++) {
    int e = e0 + t * 256 + tid;
    int r = ei[e], c = ei[EE + e];
    row[t] = r;
    g[t] = batch[c];
    nrm[t] = dis[r] * dis[c];
    rk[t] = atomicAdd(&lh[g[t]], 1);
  }
  __syncthreads();
  if (tid < GB && lh[tid]) lbase[tid] = atomicAdd(&cursor[tid * 16], lh[tid]);
  __syncthreads();
#pragma unroll
  for (int t = 0; t < 4; t++) {
    uint2 v; v.x = (unsigned)row[t]; v.y = __float_as_uint(nrm[t]);
    bucket[lbase[g[t]] + rk[t]] = v;
  }
}

// ---- per-graph gather-accumulate (unroll 8 for more outstanding gathers)
__global__ void k_gather(const uint2* bucket, const int* off, const u16* xw, float* gsum) {
  __shared__ float red[4][256];
  int tid = threadIdx.x;
  int s = blockIdx.x, g = blockIdx.y;
  int lo = off[g], hi = off[g + 1];
  int cnt = hi - lo;
  int per = (cnt + 7) >> 3;
  int b0 = lo + s * per, b1 = min(b0 + per, hi);
  int lane = tid & 63, wid = tid >> 6;
  f32x4 acc = {0.f, 0.f, 0.f, 0.f};
  const u16* xbase = xw + lane * 4;
#pragma unroll 8
  for (int e = b0 + wid; e < b1; e += 4) {
    uint2 be = bucket[e];
    float nrm = __uint_as_float(be.y);
    ushort4 v = *(const ushort4*)(xbase + (size_t)be.x * 256);
    acc.x = fmaf(nrm, u2f(v.x), acc.x);
    acc.y = fmaf(nrm, u2f(v.y), acc.y);
    acc.z = fmaf(nrm, u2f(v.z), acc.z);
    acc.w = fmaf(nrm, u2f(v.w), acc.w);
  }
  *(f32x4*)&red[wid][lane * 4] = acc;
  __syncthreads();
  float v = red[0][tid] + red[1][tid] + red[2][tid] + red[3][tid];
  if (v != 0.f) atomicAdd(&gsum[tid * 128 + g], v);
}

// ---- conv1: target[bl][26][1000] -> h1T[bl][l<998][64] bf16 channel-last (relu)
__global__ void k_conv1(const float* target, const float* w1T, const float* b1, u16* h1T) {
  __shared__ float ts[26][132];
  __shared__ float wls[78 * 64];
  int tid = threadIdx.x, lt = blockIdx.x, bl = blockIdx.y;
  int l0 = lt * 128;
  int q = tid >> 6, lane = tid & 63;
  for (int c = q; c < 26; c += 4)
    for (int i = lane; i < 130; i += 64)
      ts[c][i] = target[(bl * 26 + c) * 1000 + min(l0 + i, 999)];
  for (int i = tid; i < 4992; i += 256) wls[i] = w1T[i];
  __syncthreads();
  int o = tid & 63, wid = tid >> 6;
  float w[78];
#pragma unroll
  for (int i = 0; i < 78; i++) w[i] = wls[i * 64 + o];
  float bias = b1[o];
  for (int t = 0; t < 32; t++) {
    int li = wid * 32 + t;
    float acc = bias;
#pragma unroll
    for (int c = 0; c < 26; c++)
#pragma unroll
      for (int k = 0; k < 3; k++) acc += ts[c][li + k] * w[c * 3 + k];
    int lg = l0 + li;
    if (lg < 998) h1T[((size_t)bl * 1000 + lg) * 64 + o] = f2bf(fmaxf(acc, 0.f));
  }
}

// ---- conv2 as 3 shifted GEMMs via MFMA: h1T[bl][1000][64] x w2t -> h2T[bl][996][256] bf16
__global__ void k_conv2(const u16* h1T, const u16* w2t, const float* b2, u16* h2T) {
  __shared__ __align__(16) u16 als[132 * 32];
  __shared__ __align__(16) u16 bls[3 * 128 * 32];
  int tid = threadIdx.x;
  int lt = blockIdx.x, ot = blockIdx.y, bl = blockIdx.z;
  int l0 = lt * 128, o0 = ot * 128;
  int lane = tid & 63, wid = tid >> 6;
  int wm = wid >> 1, wn = wid & 1;
  int quad = lane >> 4, l16 = lane & 15;
  const f32x4 zero = {0.f, 0.f, 0.f, 0.f};
  f32x4 acc[4][4];
#pragma unroll
  for (int i = 0; i < 4; i++)
#pragma unroll
    for (int j = 0; j < 4; j++) acc[i][j] = zero;
  for (int cb = 0; cb < 2; cb++) {
    int c0 = cb * 32;
#pragma unroll
    for (int rr = 0; rr < 2; rr++) {
      int cid = rr * 256 + wid * 64 + lane;
      int row = cid >> 2, ch = (cid & 3) ^ (row & 3);
      GLDS16(h1T + ((size_t)bl * 1000 + min(l0 + row, 997)) * 64 + c0 + ch * 8,
             als + (rr * 256 + wid * 64) * 8);
    }
    if (wid == 0 && lane < 8) {
      int cid = 512 + lane;
      int row = cid >> 2, ch = (cid & 3) ^ (row & 3);
      GLDS16(h1T + ((size_t)bl * 1000 + min(l0 + row, 997)) * 64 + c0 + ch * 8, als + 512 * 8);
    }
#pragma unroll
    for (int rr = 0; rr < 6; rr++) {
      int cid = rr * 256 + wid * 64 + lane;
      int rko = cid >> 2, k = rko >> 7, o = rko & 127;
      int ch = (cid & 3) ^ (rko & 3);
      GLDS16(w2t + ((size_t)(k * 256 + o0 + o)) * 64 + c0 + ch * 8,
             bls + (rr * 256 + wid * 64) * 8);
    }
    __syncthreads();
#pragma unroll
    for (int k = 0; k < 3; k++) {
      short8 af[4], bfr[4];
#pragma unroll
      for (int i = 0; i < 4; i++) {
        int row = k + wm * 64 + i * 16 + l16;
        af[i] = *(const short8*)(als + row * 32 + ((quad ^ (row & 3)) * 8));
      }
#pragma unroll
      for (int j = 0; j < 4; j++) {
        int rowB = wn * 64 + j * 16 + l16;
        bfr[j] = *(const short8*)(bls + (k * 128 + rowB) * 32 + ((quad ^ (rowB & 3)) * 8));
      }
#pragma unroll
      for (int i = 0; i < 4; i++)
#pragma unroll
        for (int j = 0; j < 4; j++)
          acc[i][j] = __builtin_amdgcn_mfma_f32_16x16x32_bf16(af[i], bfr[j], acc[i][j], 0, 0, 0);
    }
    __syncthreads();
  }
#pragma unroll
  for (int j = 0; j < 4; j++) {
    int col = o0 + wn * 64 + j * 16 + l16;
    float bias = b2[col];
#pragma unroll
    for (int i = 0; i < 4; i++)
#pragma unroll
      for (int r = 0; r < 4; r++) {
        int lg = l0 + wm * 64 + i * 16 + quad * 4 + r;
        if (lg < 996)
          h2T[((size_t)bl * 996 + lg) * 256 + col] = f2bf(fmaxf(acc[i][j][r] + bias, 0.f));
      }
  }
}

// ---- conv3: EXACT round-7 structure (423 us measured). A staged in LDS half-window,
// ---- B global->VGPR pipelined, wave tile 64x128 (j=0..7), grid 4ot x 128bl = 512 = 2/CU.
__global__ void __launch_bounds__(256, 2)
k_conv3(const u16* h2T, const u16* w3r, const float* b3, float* pooledT) {
  __shared__ __align__(16) u16 als[136 * 128];   // 34816 B
  __shared__ float mbuf[2][256];
  int bid = blockIdx.x;
  int xc = bid & 7, rr0 = bid >> 3;            // 64 blocks per XCD: 16 bl x 4 ot
  int ot = rr0 & 3, bl = xc * 16 + (rr0 >> 2);
  int o0 = ot * 256;
  int tid = threadIdx.x;
  int lane = tid & 63, wid = tid >> 6;
  int wm = wid >> 1, wn = wid & 1;
  int quad = lane >> 4, l16 = lane & 15;
  float omax[8];
#pragma unroll
  for (int j = 0; j < 8; j++) omax[j] = -3.0e38f;
  const f32x4 zero = {0.f, 0.f, 0.f, 0.f};
  const u16* wbase = w3r + ((size_t)(ot * 2 + wn)) * 32768 + lane * 8;
  for (int lt = 0; lt < 8; lt++) {
    int l0 = lt * 128;
    f32x4 acc[4][8];
#pragma unroll
    for (int i = 0; i < 4; i++)
#pragma unroll
      for (int j = 0; j < 8; j++) acc[i][j] = zero;
#pragma unroll 1
    for (int st = 0; st < 2; st++) {
#pragma unroll
      for (int rr = 0; rr < 8; rr++) {
        int cid = rr * 256 + tid;
        int row = cid >> 4, pp = cid & 15;
        int cc = (pp - row) & 15;
        GLDS16(h2T + ((size_t)bl * 996 + min(l0 + row, 995)) * 256 + st * 128 + cc * 8,
               als + (rr * 256 + wid * 64) * 8);
      }
      if (wid < 2) {
        int cid = 2048 + wid * 64 + lane;
        int row = cid >> 4, pp = cid & 15;
        int cc = (pp - row) & 15;
        GLDS16(h2T + ((size_t)bl * 996 + min(l0 + row, 995)) * 256 + st * 128 + cc * 8,
               als + (2048 + wid * 64) * 8);
      }
      short8 breg[8];
#pragma unroll
      for (int j = 0; j < 8; j++)
        breg[j] = *(const short8*)(wbase + (size_t)j * 4096 + (size_t)(st * 4) * 512);
      __syncthreads();
#pragma unroll
      for (int cb = 0; cb < 4; cb++) {
#pragma unroll
        for (int k = 0; k < 5; k++) {
          short8 bcur[8];
#pragma unroll
          for (int j = 0; j < 8; j++) bcur[j] = breg[j];
          int nk = (k == 4) ? 0 : k + 1;
          int ncb = (k == 4) ? cb + 1 : cb;
          if (ncb == 4) { ncb = 3; nk = 4; }   // clamp: redundant reload on final iter
#pragma unroll
          for (int j = 0; j < 8; j++)
            breg[j] = *(const short8*)(wbase + (size_t)nk * 262144 + (size_t)j * 4096 +
                                       (size_t)(st * 4 + ncb) * 512);
          short8 af[4];
#pragma unroll
          for (int i = 0; i < 4; i++) {
            int row = k + wm * 64 + i * 16 + l16;
            int pp = (cb * 4 + quad + row) & 15;
            af[i] = *(const short8*)(als + row * 128 + pp * 8);
          }
#pragma unroll
          for (int i = 0; i < 4; i++)
#pragma unroll
            for (int j = 0; j < 8; j++)
              acc[i][j] = __builtin_amdgcn_mfma_f32_16x16x32_bf16(af[i], bcur[j], acc[i][j],
                                                                  0, 0, 0);
        }
      }
      __syncthreads();
    }
#pragma unroll
    for (int i = 0; i < 4; i++) {
#pragma unroll
      for (int r = 0; r < 4; r++) {
        int lg = l0 + wm * 64 + i * 16 + quad * 4 + r;
        if (lg < 992) {
#pragma unroll
          for (int j = 0; j < 8; j++) omax[j] = fmaxf(omax[j], acc[i][j][r]);
        }
      }
    }
  }
#pragma unroll
  for (int j = 0; j < 8; j++) {
    omax[j] = fmaxf(omax[j], __shfl_xor(omax[j], 16, 64));
    omax[j] = fmaxf(omax[j], __shfl_xor(omax[j], 32, 64));
  }
  if (quad == 0) {
#pragma unroll
    for (int j = 0; j < 8; j++) mbuf[wm][wn * 128 + j * 16 + l16] = omax[j];
  }
  __syncthreads();
  {
    float v = fmaxf(mbuf[0][tid], mbuf[1][tid]);
    v += b3[o0 + tid];
    pooledT[(size_t)(o0 + tid) * 128 + bl] = fmaxf(v, 0.f);
  }
}

// ---- z0T[r][b]
__global__ void k_z0(const float* gsum, const int* start, const float* lin_b, const float* tgtT,
                     float* z0T) {
  int idx = blockIdx.x * 256 + threadIdx.x;
  int r = idx >> 7, bb = idx & 127;
  float v;
  if (r < 256) {
    float c = (float)(start[bb + 1] - start[bb]);
    v = gsum[idx] / c + lin_b[r];
  } else {
    v = tgtT[(r - 256) * 128 + bb];
  }
  z0T[idx] = v;
}

// ---- big fc layers (relu): 512 threads, 4 output rows per block (halved zT re-reads)
__global__ void k_fc4(const float* zT, const float* W, const float* bias, float* outT,
                      int K, int O) {
  __shared__ float wls[4 * 1024];
  int tid = threadIdx.x;
  int o0 = blockIdx.x * 4;
  for (int idx = tid; idx < 4 * K; idx += 512) {
    int oo = idx / K, i = idx - oo * K;
    wls[oo * K + i] = W[(size_t)(o0 + oo) * K + i];
  }
  __syncthreads();
  int osub = tid >> 7, bb = tid & 127;
  int o = o0 + osub;
  float acc = 0.f;
  const float* wp = &wls[osub * K];
#pragma unroll 8
  for (int i = 0; i < K; i++) acc = fmaf(wp[i], zT[i * 128 + bb], acc);
  acc += bias[o];
  outT[(size_t)o * 128 + bb] = fmaxf(acc, 0.f);
}

// ---- final fc layer (O=1, no relu) -> d_out
__global__ void k_fc_final(const float* zT, const float* W, const float* bias, float* final_out,
                           int K) {
  __shared__ float wls[512];
  int tid = threadIdx.x;
  for (int i = tid; i < K; i += 256) wls[i] = W[i];
  __syncthreads();
  if (tid >= 128) return;
  int bb = tid;
  float acc = 0.f;
#pragma unroll 8
  for (int i = 0; i < K; i++) acc = fmaf(wls[i], zT[i * 128 + bb], acc);
  final_out[bb] = acc + bias[0];
}

extern "C" void kernel_launch(void* const* d_in, const int* in_sizes, int n_in,
                              void* d_out, int out_size, void* d_ws, size_t ws_size,
                              hipStream_t stream) {
  const float* x      = (const float*)d_in[0];
  const int*   ei     = (const int*)d_in[1];
  const int*   batch  = (const int*)d_in[2];
  const float* target = (const float*)d_in[3];
  const float* lin_w  = (const float*)d_in[4];
  const float* lin_b  = (const float*)d_in[5];
  const float* w1     = (const float*)d_in[6];
  const float* b1     = (const float*)d_in[7];
  const float* w2     = (const float*)d_in[8];
  const float* b2     = (const float*)d_in[9];
  const float* w3     = (const float*)d_in[10];
  const float* b3     = (const float*)d_in[11];
  const float* fcw    = (const float*)d_in[12];
  const float* fcb    = (const float*)d_in[13];
  const float* m1w = (const float*)d_in[14]; const float* m1b = (const float*)d_in[15];
  const float* m2w = (const float*)d_in[16]; const float* m2b = (const float*)d_in[17];
  const float* m3w = (const float*)d_in[18]; const float* m3b = (const float*)d_in[19];
  const float* m4w = (const float*)d_in[20]; const float* m4b = (const float*)d_in[21];

  char* ws = (char*)d_ws;
  size_t ofs = 0;
  auto alloc = [&](size_t bytes) -> void* {
    void* p = ws + ofs;
    ofs = (ofs + bytes + 255) & ~(size_t)255;
    return p;
  };
  // ---- persistent region ----
  int*   deg    = (int*)alloc((size_t)NN * 4);
  float* dis    = (float*)alloc((size_t)NN * 4);
  int*   start  = (int*)alloc((size_t)(GB + 1) * 4);
  int*   hist   = (int*)alloc((size_t)GB * 16 * 4);
  int*   off    = (int*)alloc((size_t)(GB + 1) * 4);
  int*   cursor = (int*)alloc((size_t)GB * 16 * 4);
  uint2* bucket = (uint2*)alloc((size_t)EE * 8);
  float* gsum   = (float*)alloc((size_t)256 * 128 * 4);
  float* lin_wT = (float*)alloc((size_t)33 * 256 * 4);
  float* w1T    = (float*)alloc((size_t)78 * 64 * 4);
  u16*   w2t    = (u16*)alloc((size_t)3 * 256 * 64 * 2);
  u16*   w3r    = (u16*)alloc((size_t)5 * 1024 * 256 * 2);
  float* pooledT= (float*)alloc((size_t)1024 * 128 * 4);
  float* tgtT   = (float*)alloc((size_t)768 * 128 * 4);
  float* z0T    = (float*)alloc((size_t)1024 * 128 * 4);
  float* z1T    = (float*)alloc((size_t)1024 * 128 * 4);
  float* z2T    = (float*)alloc((size_t)1024 * 128 * 4);
  float* z3T    = (float*)alloc((size_t)512 * 128 * 4);
  size_t F_end = ofs;

  // ---- dynamic region: xw (GNN) aliased by h1T+h2T (CNN) ----
  u16* xw  = (u16*)(ws + F_end);
  u16* h1T = (u16*)(ws + F_end);
  u16* h2T = (u16*)(ws + F_end + (size_t)128 * 1000 * 64 * 2);

  hipMemsetAsync(deg, 0, (size_t)NN * 4, stream);
  hipMemsetAsync(hist, 0, (size_t)GB * 16 * 4, stream);
  hipMemsetAsync(gsum, 0, (size_t)256 * 128 * 4, stream);

  // ---- GNN phase ----
  k_transpose<<<5365, 256, 0, stream>>>(lin_w, w1, w2, w3, lin_wT, w1T, w2t, w3r);
  k_deg_start<<<500, 256, 0, stream>>>(ei, batch, deg, start, hist);
  k_prefix<<<1, 128, 0, stream>>>(hist, off, cursor);
  k_xw<<<4000, 256, 0, stream>>>(x, lin_wT, deg, xw, dis);
  k_scatter<<<500, 256, 0, stream>>>(ei, batch, dis, cursor, bucket);
  k_gather<<<dim3(8, GB), 256, 0, stream>>>(bucket, off, xw, gsum);

  // ---- CNN phase ----
  k_conv1<<<dim3(8, 128), 256, 0, stream>>>(target, w1T, b1, h1T);
  k_conv2<<<dim3(8, 2, 128), 256, 0, stream>>>(h1T, w2t, b2, h2T);
  k_conv3<<<512, 256, 0, stream>>>(h2T, w3r, b3, pooledT);

  // ---- head ----
  k_fc4<<<192, 512, 0, stream>>>(pooledT, fcw, fcb, tgtT, 1024, 768);
  k_z0<<<512, 256, 0, stream>>>(gsum, start, lin_b, tgtT, z0T);
  k_fc4<<<256, 512, 0, stream>>>(z0T, m1w, m1b, z1T, 1024, 1024);
  k_fc4<<<256, 512, 0, stream>>>(z1T, m2w, m2b, z2T, 1024, 1024);
  k_fc4<<<128, 512, 0, stream>>>(z2T, m3w, m3b, z3T, 1024, 512);
  k_fc_final<<<1, 256, 0, stream>>>(z3T, m4w, m4b, (float*)d_out, 512);
}

// Round 10
// 843.156 us; speedup vs baseline: 2.6935x; 1.1628x over previous
//
#include <hip/hip_runtime.h>

typedef unsigned short u16;
typedef __attribute__((ext_vector_type(8))) short short8;
typedef __attribute__((ext_vector_type(4))) float f32x4;

#define NN 128000
#define EE 512000
#define GB 128

#define GLDS16(g, l)                                                     \
  __builtin_amdgcn_global_load_lds(                                      \
      (const __attribute__((address_space(1))) unsigned int*)(g),        \
      (__attribute__((address_space(3))) unsigned int*)(l), 16, 0, 0)

__device__ __forceinline__ float u2f(u16 u) {
  union { unsigned u32; float f; } v; v.u32 = ((unsigned)u) << 16; return v.f;
}
__device__ __forceinline__ u16 f2bf(float x) {
  union { float f; unsigned u; } v; v.f = x;
  unsigned r = v.u + 0x7FFF + ((v.u >> 16) & 1);
  return (u16)(r >> 16);
}

// ---- weight prep: lin_wT[33][256] f32, w1T[78][64] f32,
// ---- w2t[k][o][c] bf16 (3x256x64),
// ---- w3r: wave-coalesced B fragments [k][ot4][wn4][j4][cb8][quad4][l16_16][i8] bf16
// ----      (k stride 262144 u16, ot 65536, wn 16384, j 4096, cb 512)
__global__ void k_transpose(const float* lin_w, const float* w1, const float* w2, const float* w3,
                            float* lin_wT, float* w1T, u16* w2t, u16* w3r) {
  int idx = blockIdx.x * 256 + threadIdx.x;
  if (idx < 8448) { int i = idx >> 8, o = idx & 255; lin_wT[idx] = lin_w[o * 33 + i]; return; }
  idx -= 8448;
  if (idx < 4992) { int o = idx & 63, ck = idx >> 6; w1T[idx] = w1[o * 78 + ck]; return; }
  idx -= 4992;
  if (idx < 49152) {
    int c = idx & 63, o = (idx >> 6) & 255, k = idx >> 14;
    w2t[idx] = f2bf(w2[o * 192 + c * 3 + k]);
    return;
  }
  idx -= 49152;
  if (idx < 1310720) {
    int k    = idx >> 18;
    int r    = idx & 262143;
    int ot   = r >> 16;
    int wn   = (r >> 14) & 3;
    int j    = (r >> 12) & 3;
    int cb   = (r >> 9) & 7;
    int quad = (r >> 7) & 3;
    int l16  = (r >> 3) & 15;
    int i    = r & 7;
    int o = ot * 256 + wn * 64 + j * 16 + l16;
    int c = cb * 32 + quad * 8 + i;
    w3r[idx] = f2bf(w3[o * 1280 + c * 5 + k]);
  }
}

// ---- in-degree over col; per-graph edge histogram; graph boundaries
__global__ void k_deg_start(const int* ei, const int* batch, int* deg, int* start, int* hist) {
  __shared__ int lh[GB];
  int tid = threadIdx.x, blk = blockIdx.x;
  if (tid < GB) lh[tid] = 0;
  __syncthreads();
  int e0 = blk * 1024;
#pragma unroll
  for (int t = 0; t < 4; t++) {
    int e = e0 + t * 256 + tid;
    int col = ei[EE + e];
    atomicAdd(&deg[col], 1);
    atomicAdd(&lh[batch[col]], 1);
  }
  int i = blk * 256 + tid;
  int b = batch[i];
  if (i == 0) start[0] = 0;
  else if (b != batch[i - 1]) start[b] = i;
  if (i == NN - 1) start[GB] = NN;
  __syncthreads();
  if (tid < GB && lh[tid]) atomicAdd(&hist[tid * 16], lh[tid]);
}

// ---- exclusive prefix over 128 bins; init padded cursors
__global__ void k_prefix(const int* hist, int* off, int* cursor) {
  __shared__ int h[GB];
  int tid = threadIdx.x;
  h[tid] = hist[tid * 16];
  __syncthreads();
  int s = 0;
  for (int j = 0; j < tid; j++) s += h[j];
  off[tid] = s;
  cursor[tid * 16] = s;
  if (tid == GB - 1) off[GB] = s + h[GB - 1];
}

// ---- xw[n][c] = x[n] . lin_w[c] (bf16);  dis[n]
__global__ void k_xw(const float* x, const float* lin_wT, const int* deg, u16* xw, float* dis) {
  __shared__ float xs[32][34];
  int tid = threadIdx.x, n0 = blockIdx.x * 32;
  int q = tid >> 6, lane = tid & 63;
  for (int n = q; n < 32; n += 4)
    if (lane < 33) xs[n][lane] = x[(n0 + n) * 33 + lane];
  float w[33];
#pragma unroll
  for (int i = 0; i < 33; i++) w[i] = lin_wT[i * 256 + tid];
  __syncthreads();
  for (int n = 0; n < 32; n++) {
    float acc = 0.f;
#pragma unroll
    for (int i = 0; i < 33; i++) acc += w[i] * xs[n][i];
    xw[(size_t)(n0 + n) * 256 + tid] = f2bf(acc);
  }
  if (tid < 32) { int d = deg[n0 + tid]; dis[n0 + tid] = d > 0 ? rsqrtf((float)d) : 0.f; }
}

// ---- bucket edges by graph of col
__global__ void k_scatter(const int* ei, const int* batch, const float* dis,
                          int* cursor, uint2* bucket) {
  __shared__ int lh[GB];
  __shared__ int lbase[GB];
  int tid = threadIdx.x, blk = blockIdx.x;
  if (tid < GB) lh[tid] = 0;
  __syncthreads();
  int e0 = blk * 1024;
  int row[4], g[4], rk[4]; float nrm[4];
#pragma unroll
  for (int t = 0; t < 4; t++) {
    int e = e0 + t * 256 + tid;
    int r = ei[e], c = ei[EE + e];
    row[t] = r;
    g[t] = batch[c];
    nrm[t] = dis[r] * dis[c];
    rk[t] = atomicAdd(&lh[g[t]], 1);
  }
  __syncthreads();
  if (tid < GB && lh[tid]) lbase[tid] = atomicAdd(&cursor[tid * 16], lh[tid]);
  __syncthreads();
#pragma unroll
  for (int t = 0; t < 4; t++) {
    uint2 v; v.x = (unsigned)row[t]; v.y = __float_as_uint(nrm[t]);
    bucket[lbase[g[t]] + rk[t]] = v;
  }
}

// ---- per-graph gather-accumulate (16 splits/graph for TLP)
__global__ void k_gather(const uint2* bucket, const int* off, const u16* xw, float* gsum) {
  __shared__ float red[4][256];
  int tid = threadIdx.x;
  int s = blockIdx.x, g = blockIdx.y;
  int lo = off[g], hi = off[g + 1];
  int cnt = hi - lo;
  int per = (cnt + 15) >> 4;
  int b0 = lo + s * per, b1 = min(b0 + per, hi);
  int lane = tid & 63, wid = tid >> 6;
  f32x4 acc = {0.f, 0.f, 0.f, 0.f};
  const u16* xbase = xw + lane * 4;
#pragma unroll 8
  for (int e = b0 + wid; e < b1; e += 4) {
    uint2 be = bucket[e];
    float nrm = __uint_as_float(be.y);
    ushort4 v = *(const ushort4*)(xbase + (size_t)be.x * 256);
    acc.x = fmaf(nrm, u2f(v.x), acc.x);
    acc.y = fmaf(nrm, u2f(v.y), acc.y);
    acc.z = fmaf(nrm, u2f(v.z), acc.z);
    acc.w = fmaf(nrm, u2f(v.w), acc.w);
  }
  *(f32x4*)&red[wid][lane * 4] = acc;
  __syncthreads();
  float v = red[0][tid] + red[1][tid] + red[2][tid] + red[3][tid];
  if (v != 0.f) atomicAdd(&gsum[tid * 128 + g], v);
}

// ---- conv1: target[bl][26][1000] -> h1T[bl][l<998][64] bf16 channel-last (relu)
__global__ void k_conv1(const float* target, const float* w1T, const float* b1, u16* h1T) {
  __shared__ float ts[26][132];
  __shared__ float wls[78 * 64];
  int tid = threadIdx.x, lt = blockIdx.x, bl = blockIdx.y;
  int l0 = lt * 128;
  int q = tid >> 6, lane = tid & 63;
  for (int c = q; c < 26; c += 4)
    for (int i = lane; i < 130; i += 64)
      ts[c][i] = target[(bl * 26 + c) * 1000 + min(l0 + i, 999)];
  for (int i = tid; i < 4992; i += 256) wls[i] = w1T[i];
  __syncthreads();
  int o = tid & 63, wid = tid >> 6;
  float w[78];
#pragma unroll
  for (int i = 0; i < 78; i++) w[i] = wls[i * 64 + o];
  float bias = b1[o];
  for (int t = 0; t < 32; t++) {
    int li = wid * 32 + t;
    float acc = bias;
#pragma unroll
    for (int c = 0; c < 26; c++)
#pragma unroll
      for (int k = 0; k < 3; k++) acc += ts[c][li + k] * w[c * 3 + k];
    int lg = l0 + li;
    if (lg < 998) h1T[((size_t)bl * 1000 + lg) * 64 + o] = f2bf(fmaxf(acc, 0.f));
  }
}

// ---- conv2 as 3 shifted GEMMs via MFMA: h1T[bl][1000][64] x w2t -> h2T[bl][996][256] bf16
__global__ void k_conv2(const u16* h1T, const u16* w2t, const float* b2, u16* h2T) {
  __shared__ __align__(16) u16 als[132 * 32];
  __shared__ __align__(16) u16 bls[3 * 128 * 32];
  int tid = threadIdx.x;
  int lt = blockIdx.x, ot = blockIdx.y, bl = blockIdx.z;
  int l0 = lt * 128, o0 = ot * 128;
  int lane = tid & 63, wid = tid >> 6;
  int wm = wid >> 1, wn = wid & 1;
  int quad = lane >> 4, l16 = lane & 15;
  const f32x4 zero = {0.f, 0.f, 0.f, 0.f};
  f32x4 acc[4][4];
#pragma unroll
  for (int i = 0; i < 4; i++)
#pragma unroll
    for (int j = 0; j < 4; j++) acc[i][j] = zero;
  for (int cb = 0; cb < 2; cb++) {
    int c0 = cb * 32;
#pragma unroll
    for (int rr = 0; rr < 2; rr++) {
      int cid = rr * 256 + wid * 64 + lane;
      int row = cid >> 2, ch = (cid & 3) ^ (row & 3);
      GLDS16(h1T + ((size_t)bl * 1000 + min(l0 + row, 997)) * 64 + c0 + ch * 8,
             als + (rr * 256 + wid * 64) * 8);
    }
    if (wid == 0 && lane < 8) {
      int cid = 512 + lane;
      int row = cid >> 2, ch = (cid & 3) ^ (row & 3);
      GLDS16(h1T + ((size_t)bl * 1000 + min(l0 + row, 997)) * 64 + c0 + ch * 8, als + 512 * 8);
    }
#pragma unroll
    for (int rr = 0; rr < 6; rr++) {
      int cid = rr * 256 + wid * 64 + lane;
      int rko = cid >> 2, k = rko >> 7, o = rko & 127;
      int ch = (cid & 3) ^ (rko & 3);
      GLDS16(w2t + ((size_t)(k * 256 + o0 + o)) * 64 + c0 + ch * 8,
             bls + (rr * 256 + wid * 64) * 8);
    }
    __syncthreads();
#pragma unroll
    for (int k = 0; k < 3; k++) {
      short8 af[4], bfr[4];
#pragma unroll
      for (int i = 0; i < 4; i++) {
        int row = k + wm * 64 + i * 16 + l16;
        af[i] = *(const short8*)(als + row * 32 + ((quad ^ (row & 3)) * 8));
      }
#pragma unroll
      for (int j = 0; j < 4; j++) {
        int rowB = wn * 64 + j * 16 + l16;
        bfr[j] = *(const short8*)(bls + (k * 128 + rowB) * 32 + ((quad ^ (rowB & 3)) * 8));
      }
#pragma unroll
      for (int i = 0; i < 4; i++)
#pragma unroll
        for (int j = 0; j < 4; j++)
          acc[i][j] = __builtin_amdgcn_mfma_f32_16x16x32_bf16(af[i], bfr[j], acc[i][j], 0, 0, 0);
    }
    __syncthreads();
  }
#pragma unroll
  for (int j = 0; j < 4; j++) {
    int col = o0 + wn * 64 + j * 16 + l16;
    float bias = b2[col];
#pragma unroll
    for (int i = 0; i < 4; i++)
#pragma unroll
      for (int r = 0; r < 4; r++) {
        int lg = l0 + wm * 64 + i * 16 + quad * 4 + r;
        if (lg < 996)
          h2T[((size_t)bl * 996 + lg) * 256 + col] = f2bf(fmaxf(acc[i][j][r] + bias, 0.f));
      }
  }
}

// ---- conv3: r7 chassis (st-split 34.8 KB A window) + r8 traffic shape:
// ---- waves = 4 distinct wn (N=64 each, no wm redundancy), wave M=128 (i=8, all rows).
// ---- B direct global->VGPR per k (no SW pipeline; TLP covers L2 latency);
// ---- cb loop NOT unrolled to bound the live set (anti-spill). 2 blocks/CU.
__global__ void __launch_bounds__(256, 2)
k_conv3(const u16* h2T, const u16* w3r, const float* b3, float* pooledT) {
  __shared__ __align__(16) u16 als[136 * 128];   // 34816 B
  __shared__ float mbuf[256];
  int bid = blockIdx.x;
  int xc = bid & 7, rr0 = bid >> 3;            // 64 blocks per XCD: 16 bl x 4 ot
  int ot = rr0 & 3, bl = xc * 16 + (rr0 >> 2);
  int o0 = ot * 256;
  int tid = threadIdx.x;
  int lane = tid & 63, wn = tid >> 6;
  int quad = lane >> 4, l16 = lane & 15;
  float omax[4];
#pragma unroll
  for (int j = 0; j < 4; j++) omax[j] = -3.0e38f;
  const f32x4 zero = {0.f, 0.f, 0.f, 0.f};
  // per-wave B base: [k][ot][wn][j][cb][quad|l16|i8]
  const u16* wbase = w3r + ((size_t)(ot * 4 + wn)) * 16384 + lane * 8;
  for (int lt = 0; lt < 8; lt++) {
    int l0 = lt * 128;
    f32x4 acc[8][4];
#pragma unroll
    for (int i = 0; i < 8; i++)
#pragma unroll
      for (int j = 0; j < 4; j++) acc[i][j] = zero;
#pragma unroll 1
    for (int st = 0; st < 2; st++) {
      // stage A half-window: 136 rows x 128 ch = 2176 chunks; swizzle pp=(cc+row)&15
#pragma unroll
      for (int rr = 0; rr < 8; rr++) {
        int cid = rr * 256 + tid;
        int row = cid >> 4, pp = cid & 15;
        int cc = (pp - row) & 15;
        GLDS16(h2T + ((size_t)bl * 996 + min(l0 + row, 995)) * 256 + st * 128 + cc * 8,
               als + (rr * 256 + wn * 64) * 8);
      }
      if (wn < 2) {
        int cid = 2048 + wn * 64 + lane;
        int row = cid >> 4, pp = cid & 15;
        int cc = (pp - row) & 15;
        GLDS16(h2T + ((size_t)bl * 996 + min(l0 + row, 995)) * 256 + st * 128 + cc * 8,
               als + (2048 + wn * 64) * 8);
      }
      __syncthreads();
#pragma unroll 1
      for (int cb = 0; cb < 4; cb++) {
#pragma unroll
        for (int k = 0; k < 5; k++) {
          short8 breg[4];
#pragma unroll
          for (int j = 0; j < 4; j++)
            breg[j] = *(const short8*)(wbase + (size_t)k * 262144 + (size_t)j * 4096 +
                                       (size_t)(st * 4 + cb) * 512);
#pragma unroll
          for (int i = 0; i < 8; i++) {
            int row = k + i * 16 + l16;
            int pp = (cb * 4 + quad + row) & 15;
            short8 af = *(const short8*)(als + row * 128 + pp * 8);
#pragma unroll
            for (int j = 0; j < 4; j++)
              acc[i][j] = __builtin_amdgcn_mfma_f32_16x16x32_bf16(af, breg[j], acc[i][j],
                                                                  0, 0, 0);
          }
        }
      }
      __syncthreads();
    }
    // fold l-tile into running per-o max (mask rows >= 992)
#pragma unroll
    for (int i = 0; i < 8; i++) {
#pragma unroll
      for (int r = 0; r < 4; r++) {
        int lg = l0 + i * 16 + quad * 4 + r;
        if (lg < 992) {
#pragma unroll
          for (int j = 0; j < 4; j++) omax[j] = fmaxf(omax[j], acc[i][j][r]);
        }
      }
    }
  }
#pragma unroll
  for (int j = 0; j < 4; j++) {
    omax[j] = fmaxf(omax[j], __shfl_xor(omax[j], 16, 64));
    omax[j] = fmaxf(omax[j], __shfl_xor(omax[j], 32, 64));
  }
  if (quad == 0) {
#pragma unroll
    for (int j = 0; j < 4; j++) mbuf[wn * 64 + j * 16 + l16] = omax[j];
  }
  __syncthreads();
  {
    float v = mbuf[tid] + b3[o0 + tid];
    pooledT[(size_t)(o0 + tid) * 128 + bl] = fmaxf(v, 0.f);
  }
}

// ---- z0T[r][b]
__global__ void k_z0(const float* gsum, const int* start, const float* lin_b, const float* tgtT,
                     float* z0T) {
  int idx = blockIdx.x * 256 + threadIdx.x;
  int r = idx >> 7, bb = idx & 127;
  float v;
  if (r < 256) {
    float c = (float)(start[bb + 1] - start[bb]);
    v = gsum[idx] / c + lin_b[r];
  } else {
    v = tgtT[(r - 256) * 128 + bb];
  }
  z0T[idx] = v;
}

// ---- big fc layers (relu): 512 threads, 4 output rows per block
__global__ void k_fc4(const float* zT, const float* W, const float* bias, float* outT,
                      int K, int O) {
  __shared__ float wls[4 * 1024];
  int tid = threadIdx.x;
  int o0 = blockIdx.x * 4;
  for (int idx = tid; idx < 4 * K; idx += 512) {
    int oo = idx / K, i = idx - oo * K;
    wls[oo * K + i] = W[(size_t)(o0 + oo) * K + i];
  }
  __syncthreads();
  int osub = tid >> 7, bb = tid & 127;
  int o = o0 + osub;
  float acc = 0.f;
  const float* wp = &wls[osub * K];
#pragma unroll 8
  for (int i = 0; i < K; i++) acc = fmaf(wp[i], zT[i * 128 + bb], acc);
  acc += bias[o];
  outT[(size_t)o * 128 + bb] = fmaxf(acc, 0.f);
}

// ---- final fc layer (O=1, no relu) -> d_out
__global__ void k_fc_final(const float* zT, const float* W, const float* bias, float* final_out,
                           int K) {
  __shared__ float wls[512];
  int tid = threadIdx.x;
  for (int i = tid; i < K; i += 256) wls[i] = W[i];
  __syncthreads();
  if (tid >= 128) return;
  int bb = tid;
  float acc = 0.f;
#pragma unroll 8
  for (int i = 0; i < K; i++) acc = fmaf(wls[i], zT[i * 128 + bb], acc);
  final_out[bb] = acc + bias[0];
}

extern "C" void kernel_launch(void* const* d_in, const int* in_sizes, int n_in,
                              void* d_out, int out_size, void* d_ws, size_t ws_size,
                              hipStream_t stream) {
  const float* x      = (const float*)d_in[0];
  const int*   ei     = (const int*)d_in[1];
  const int*   batch  = (const int*)d_in[2];
  const float* target = (const float*)d_in[3];
  const float* lin_w  = (const float*)d_in[4];
  const float* lin_b  = (const float*)d_in[5];
  const float* w1     = (const float*)d_in[6];
  const float* b1     = (const float*)d_in[7];
  const float* w2     = (const float*)d_in[8];
  const float* b2     = (const float*)d_in[9];
  const float* w3     = (const float*)d_in[10];
  const float* b3     = (const float*)d_in[11];
  const float* fcw    = (const float*)d_in[12];
  const float* fcb    = (const float*)d_in[13];
  const float* m1w = (const float*)d_in[14]; const float* m1b = (const float*)d_in[15];
  const float* m2w = (const float*)d_in[16]; const float* m2b = (const float*)d_in[17];
  const float* m3w = (const float*)d_in[18]; const float* m3b = (const float*)d_in[19];
  const float* m4w = (const float*)d_in[20]; const float* m4b = (const float*)d_in[21];

  char* ws = (char*)d_ws;
  size_t ofs = 0;
  auto alloc = [&](size_t bytes) -> void* {
    void* p = ws + ofs;
    ofs = (ofs + bytes + 255) & ~(size_t)255;
    return p;
  };
  // ---- persistent region ----
  int*   deg    = (int*)alloc((size_t)NN * 4);
  float* dis    = (float*)alloc((size_t)NN * 4);
  int*   start  = (int*)alloc((size_t)(GB + 1) * 4);
  int*   hist   = (int*)alloc((size_t)GB * 16 * 4);
  int*   off    = (int*)alloc((size_t)(GB + 1) * 4);
  int*   cursor = (int*)alloc((size_t)GB * 16 * 4);
  uint2* bucket = (uint2*)alloc((size_t)EE * 8);
  float* gsum   = (float*)alloc((size_t)256 * 128 * 4);
  float* lin_wT = (float*)alloc((size_t)33 * 256 * 4);
  float* w1T    = (float*)alloc((size_t)78 * 64 * 4);
  u16*   w2t    = (u16*)alloc((size_t)3 * 256 * 64 * 2);
  u16*   w3r    = (u16*)alloc((size_t)5 * 1024 * 256 * 2);
  float* pooledT= (float*)alloc((size_t)1024 * 128 * 4);
  float* tgtT   = (float*)alloc((size_t)768 * 128 * 4);
  float* z0T    = (float*)alloc((size_t)1024 * 128 * 4);
  float* z1T    = (float*)alloc((size_t)1024 * 128 * 4);
  float* z2T    = (float*)alloc((size_t)1024 * 128 * 4);
  float* z3T    = (float*)alloc((size_t)512 * 128 * 4);
  size_t F_end = ofs;

  // ---- dynamic region: xw (GNN) aliased by h1T+h2T (CNN) ----
  u16* xw  = (u16*)(ws + F_end);
  u16* h1T = (u16*)(ws + F_end);
  u16* h2T = (u16*)(ws + F_end + (size_t)128 * 1000 * 64 * 2);

  hipMemsetAsync(deg, 0, (size_t)NN * 4, stream);
  hipMemsetAsync(hist, 0, (size_t)GB * 16 * 4, stream);
  hipMemsetAsync(gsum, 0, (size_t)256 * 128 * 4, stream);

  // ---- GNN phase ----
  k_transpose<<<5365, 256, 0, stream>>>(lin_w, w1, w2, w3, lin_wT, w1T, w2t, w3r);
  k_deg_start<<<500, 256, 0, stream>>>(ei, batch, deg, start, hist);
  k_prefix<<<1, 128, 0, stream>>>(hist, off, cursor);
  k_xw<<<4000, 256, 0, stream>>>(x, lin_wT, deg, xw, dis);
  k_scatter<<<500, 256, 0, stream>>>(ei, batch, dis, cursor, bucket);
  k_gather<<<dim3(16, GB), 256, 0, stream>>>(bucket, off, xw, gsum);

  // ---- CNN phase ----
  k_conv1<<<dim3(8, 128), 256, 0, stream>>>(target, w1T, b1, h1T);
  k_conv2<<<dim3(8, 2, 128), 256, 0, stream>>>(h1T, w2t, b2, h2T);
  k_conv3<<<512, 256, 0, stream>>>(h2T, w3r, b3, pooledT);

  // ---- head ----
  k_fc4<<<192, 512, 0, stream>>>(pooledT, fcw, fcb, tgtT, 1024, 768);
  k_z0<<<512, 256, 0, stream>>>(gsum, start, lin_b, tgtT, z0T);
  k_fc4<<<256, 512, 0, stream>>>(z0T, m1w, m1b, z1T, 1024, 1024);
  k_fc4<<<256, 512, 0, stream>>>(z1T, m2w, m2b, z2T, 1024, 1024);
  k_fc4<<<128, 512, 0, stream>>>(z2T, m3w, m3b, z3T, 1024, 512);
  k_fc_final<<<1, 256, 0, stream>>>(z3T, m4w, m4b, (float*)d_out, 512);
}